// Round 10
// baseline (80.557 us; speedup 1.0000x reference)
//
#include <hip/hip_runtime.h>

#define BB 8
#define NN 256
#define DD 128
#define LN_EPS 1e-5f

// ---------------------------------------------------------------------------
// k_proj: hi = x@w1[:D], hjb = x@w1[D:]+b1, xw3 = x@w3[:D]+b3
// grid 256 blocks (8 rows) x 512 threads: dp = tid&127, kg = tid>>7 (4-way
// k-split). xs staged in LDS; per (k4,r): one broadcast b128 feeds 12 FMAs
// (3 outputs). Weights via coalesced VMEM. Partials combined through LDS.
// ---------------------------------------------------------------------------
__global__ __launch_bounds__(512) void k_proj(const float* __restrict__ x,
                                              const float* __restrict__ w1,
                                              const float* __restrict__ b1,
                                              const float* __restrict__ w3,
                                              const float* __restrict__ b3,
                                              float* __restrict__ hi,
                                              float* __restrict__ hjb,
                                              float* __restrict__ xw3) {
    __shared__ float xs[8 * DD];     // 4 KB
    __shared__ float part[8192];     // 32 KB: two [4][8][128] halves
    const int row0 = blockIdx.x * 8;
    const int tid  = threadIdx.x;
    #pragma unroll
    for (int t = 0; t < 2; ++t) {
        int idx = tid + t * 512;
        xs[idx] = x[row0 * DD + idx];
    }
    __syncthreads();

    const int dp = tid & 127;
    const int kg = tid >> 7;
    const int kb = kg * 32;

    float aA[8] = {}, aB[8] = {}, aC[8] = {};
    #pragma unroll
    for (int k4 = 0; k4 < 8; ++k4) {
        const int k0 = kb + k4 * 4;
        float wa[4], wb[4], wc[4];
        #pragma unroll
        for (int q = 0; q < 4; ++q) {
            wa[q] = w1[(k0 + q) * DD + dp];
            wb[q] = w1[(DD + k0 + q) * DD + dp];
            wc[q] = w3[(k0 + q) * DD + dp];
        }
        #pragma unroll
        for (int r = 0; r < 8; ++r) {
            const float4 xv = *(const float4*)&xs[r * DD + k0];  // broadcast
            const float xq[4] = {xv.x, xv.y, xv.z, xv.w};
            #pragma unroll
            for (int q = 0; q < 4; ++q) {
                aA[r] = fmaf(xq[q], wa[q], aA[r]);
                aB[r] = fmaf(xq[q], wb[q], aB[r]);
                aC[r] = fmaf(xq[q], wc[q], aC[r]);
            }
        }
    }
    #pragma unroll
    for (int r = 0; r < 8; ++r) {
        part[kg * 1024 + r * DD + dp]        = aA[r];
        part[4096 + kg * 1024 + r * DD + dp] = aB[r];
    }
    __syncthreads();
    #pragma unroll
    for (int t = 0; t < 2; ++t) {
        int idx = tid + t * 512;
        int r = idx >> 7, d = idx & 127;
        float sa = 0.f, sb = 0.f;
        #pragma unroll
        for (int w = 0; w < 4; ++w) {
            sa += part[w * 1024 + r * DD + d];
            sb += part[4096 + w * 1024 + r * DD + d];
        }
        hi [(row0 + r) * DD + d] = sa;
        hjb[(row0 + r) * DD + d] = sb + b1[d];
    }
    __syncthreads();
    #pragma unroll
    for (int r = 0; r < 8; ++r) part[kg * 1024 + r * DD + dp] = aC[r];
    __syncthreads();
    #pragma unroll
    for (int t = 0; t < 2; ++t) {
        int idx = tid + t * 512;
        int r = idx >> 7, d = idx & 127;
        float sc = 0.f;
        #pragma unroll
        for (int w = 0; w < 4; ++w) sc += part[w * 1024 + r * DD + d];
        xw3[(row0 + r) * DD + d] = sc + b3[d];
    }
}

// ---------------------------------------------------------------------------
// k_fused: 512 blocks (4 rows each) x 512 threads, 45 KB LDS -> 2 blocks/CU.
// Pair: a_tt[256][4] transposed (1 b128 = 4 rows' a), hjs single 32KB tile
// buffer with reg-prefetch; 4 rows x 4 d per thread, wave = j-slice.
// Tail: 2 cols/thread, 8-way k-split, broadcast LDS activations.
// smem floats: [0,8192) hjs -> partP[16][512] -> partT[8][512]
//              [8192,9216) a_tt | [9216,9232) asub | [9232,9236) asum_s
//              [9248,9760) ssp | [9760,10272) aggs | [10272,10784) u1s
//              [10784,11296) resS
// ---------------------------------------------------------------------------
__global__ __launch_bounds__(512, 4) void k_fused(const float* __restrict__ adj,
                                                  const float* __restrict__ x,
                                                  const float* __restrict__ hi,
                                                  const float* __restrict__ hjb,
                                                  const float* __restrict__ xw3,
                                                  const float* __restrict__ w2,
                                                  const float* __restrict__ b2,
                                                  const float* __restrict__ w3,
                                                  const float* __restrict__ w4,
                                                  const float* __restrict__ b4,
                                                  const float* __restrict__ g,
                                                  const float* __restrict__ bet,
                                                  float* __restrict__ out) {
    __shared__ float smem[11296];
    float* const hjs    = smem;           // [64][128]
    float* const partP  = smem;           // [16][512] alias
    float* const partT  = smem;           // [8][512] alias
    float* const a_tt   = smem + 8192;    // [256][4]
    float* const asub   = smem + 9216;    // [4][4]
    float* const asum_s = smem + 9232;    // [4]
    float* const ssp    = smem + 9248;    // [4][128]
    float* const aggs   = smem + 9760;    // [4][128]
    float* const u1s    = smem + 10272;   // [4][128]
    float* const resS   = smem + 10784;   // [4][128]

    const int bid  = blockIdx.x;
    const int b    = bid >> 6;           // 0..7
    const int i0   = (bid & 63) * 4;     // row base
    const int tid  = threadIdx.x;
    const int lane = tid & 63;
    const int wv   = tid >> 6;           // 0..7

    // ---- adjacency transpose (masked) + asum partials via shfl
    #pragma unroll
    for (int t = 0; t < 2; ++t) {
        int idx = tid + t * 512;            // 0..1023
        int il = idx >> 8, j = idx & 255;   // il wave-uniform
        int ig = i0 + il;
        float av = adj[((size_t)b * NN + ig) * NN + j];
        av = (j == ig) ? 0.f : av;
        a_tt[j * 4 + il] = av;
        float s = av;
        #pragma unroll
        for (int m = 32; m; m >>= 1) s += __shfl_xor(s, m);
        if (lane == 0) asub[il * 4 + ((idx >> 6) & 3)] = s;
    }

    // ---- prologue: stage hjb tile 0
    {
        const float4* src = (const float4*)(hjb + ((size_t)b * NN) * DD);
        float4* dst = (float4*)hjs;
        #pragma unroll
        for (int q = 0; q < 4; ++q) dst[tid + q * 512] = src[tid + q * 512];
    }

    const int dq    = lane & 31;     // d-quad (d0 = dq*4)
    const int jhalf = lane >> 5;     // 0/1
    float4 hi4[4];
    #pragma unroll
    for (int rr = 0; rr < 4; ++rr)
        hi4[rr] = *(const float4*)&hi[((size_t)b * NN + i0 + rr) * DD + dq * 4];
    float4 acc[4] = {{0,0,0,0},{0,0,0,0},{0,0,0,0},{0,0,0,0}};

    // ---- pair: 4 tiles of 64 j; wave wv covers j [wv*8, wv*8+8), lane-half
    // splits that into 4 j each; reg-prefetch next tile during compute.
    #pragma unroll
    for (int tt = 0; tt < 4; ++tt) {
        __syncthreads();   // hjs (and a_tt on tt=0) ready
        float4 pf[4];
        if (tt < 3) {
            const float4* src = (const float4*)(hjb + ((size_t)b * NN + (tt + 1) * 64) * DD);
            #pragma unroll
            for (int q = 0; q < 4; ++q) pf[q] = src[tid + q * 512];
        }
        const int jb = wv * 8 + jhalf * 4;
        #pragma unroll
        for (int jj = 0; jj < 4; ++jj) {
            const int jl = jb + jj;
            const float4 hv = *(const float4*)&hjs[jl * DD + dq * 4];
            const float4 a4 = *(const float4*)&a_tt[(tt * 64 + jl) * 4];
            const float aa[4] = {a4.x, a4.y, a4.z, a4.w};
            #pragma unroll
            for (int rr = 0; rr < 4; ++rr) {
                acc[rr].x = fmaf(fmaxf(hi4[rr].x + hv.x, 0.f), aa[rr], acc[rr].x);
                acc[rr].y = fmaf(fmaxf(hi4[rr].y + hv.y, 0.f), aa[rr], acc[rr].y);
                acc[rr].z = fmaf(fmaxf(hi4[rr].z + hv.z, 0.f), aa[rr], acc[rr].z);
                acc[rr].w = fmaf(fmaxf(hi4[rr].w + hv.w, 0.f), aa[rr], acc[rr].w);
            }
        }
        __syncthreads();   // all reads of hjs done
        if (tt < 3) {
            float4* dst = (float4*)hjs;
            #pragma unroll
            for (int q = 0; q < 4; ++q) dst[tid + q * 512] = pf[q];
        }
    }

    // ---- pair partials (16-way: wave x lane-half) -> ssp; finalize asum
    {
        float* pp = partP + (wv * 2 + jhalf) * 512;
        #pragma unroll
        for (int rr = 0; rr < 4; ++rr)
            *(float4*)&pp[rr * DD + dq * 4] = acc[rr];
    }
    __syncthreads();
    if (tid < 4)
        asum_s[tid] = asub[tid * 4] + asub[tid * 4 + 1]
                    + asub[tid * 4 + 2] + asub[tid * 4 + 3];
    {
        float s = 0.f;
        #pragma unroll
        for (int p = 0; p < 16; ++p) s += partP[p * 512 + tid];
        ssp[tid] = s;
    }
    __syncthreads();

    // ---- tail: 2 cols/thread (lane, lane+64), wave = k-chunk of 16
    const int kb = wv * 16;

    // stage A: agg = ssp @ w2 (+ b2*asum at combine)
    {
        float w0[16], w1r[16];
        #pragma unroll
        for (int k = 0; k < 16; ++k) {
            w0[k]  = w2[(kb + k) * DD + lane];
            w1r[k] = w2[(kb + k) * DD + lane + 64];
        }
        #pragma unroll
        for (int r = 0; r < 4; ++r) {
            float a0 = 0.f, a1 = 0.f;
            #pragma unroll
            for (int q = 0; q < 4; ++q) {
                const float4 sv = *(const float4*)&ssp[r * DD + kb + q * 4];  // broadcast
                a0 = fmaf(sv.x, w0[q*4+0], a0);  a1 = fmaf(sv.x, w1r[q*4+0], a1);
                a0 = fmaf(sv.y, w0[q*4+1], a0);  a1 = fmaf(sv.y, w1r[q*4+1], a1);
                a0 = fmaf(sv.z, w0[q*4+2], a0);  a1 = fmaf(sv.z, w1r[q*4+2], a1);
                a0 = fmaf(sv.w, w0[q*4+3], a0);  a1 = fmaf(sv.w, w1r[q*4+3], a1);
            }
            partT[wv * 512 + r * DD + lane]      = a0;
            partT[wv * 512 + r * DD + lane + 64] = a1;
        }
    }
    __syncthreads();
    {
        int r = tid >> 7, d = tid & 127;
        float s = 0.f;
        #pragma unroll
        for (int w = 0; w < 8; ++w) s += partT[w * 512 + tid];
        aggs[tid] = s + b2[d] * asum_s[r];
    }
    __syncthreads();

    // stage B: u1 = relu(xw3 + agg @ w3b)
    {
        const float* __restrict__ w3b = w3 + DD * DD;
        float w0[16], w1r[16];
        #pragma unroll
        for (int k = 0; k < 16; ++k) {
            w0[k]  = w3b[(kb + k) * DD + lane];
            w1r[k] = w3b[(kb + k) * DD + lane + 64];
        }
        #pragma unroll
        for (int r = 0; r < 4; ++r) {
            float a0 = 0.f, a1 = 0.f;
            #pragma unroll
            for (int q = 0; q < 4; ++q) {
                const float4 av = *(const float4*)&aggs[r * DD + kb + q * 4];
                a0 = fmaf(av.x, w0[q*4+0], a0);  a1 = fmaf(av.x, w1r[q*4+0], a1);
                a0 = fmaf(av.y, w0[q*4+1], a0);  a1 = fmaf(av.y, w1r[q*4+1], a1);
                a0 = fmaf(av.z, w0[q*4+2], a0);  a1 = fmaf(av.z, w1r[q*4+2], a1);
                a0 = fmaf(av.w, w0[q*4+3], a0);  a1 = fmaf(av.w, w1r[q*4+3], a1);
            }
            partT[wv * 512 + r * DD + lane]      = a0;
            partT[wv * 512 + r * DD + lane + 64] = a1;
        }
    }
    __syncthreads();
    {
        float s = xw3[((size_t)b * NN + i0) * DD + tid];
        #pragma unroll
        for (int w = 0; w < 8; ++w) s += partT[w * 512 + tid];
        u1s[tid] = fmaxf(s, 0.f);
    }
    __syncthreads();

    // stage C: res = x + u1 @ w4 + b4
    {
        float w0[16], w1r[16];
        #pragma unroll
        for (int k = 0; k < 16; ++k) {
            w0[k]  = w4[(kb + k) * DD + lane];
            w1r[k] = w4[(kb + k) * DD + lane + 64];
        }
        #pragma unroll
        for (int r = 0; r < 4; ++r) {
            float a0 = 0.f, a1 = 0.f;
            #pragma unroll
            for (int q = 0; q < 4; ++q) {
                const float4 uv = *(const float4*)&u1s[r * DD + kb + q * 4];
                a0 = fmaf(uv.x, w0[q*4+0], a0);  a1 = fmaf(uv.x, w1r[q*4+0], a1);
                a0 = fmaf(uv.y, w0[q*4+1], a0);  a1 = fmaf(uv.y, w1r[q*4+1], a1);
                a0 = fmaf(uv.z, w0[q*4+2], a0);  a1 = fmaf(uv.z, w1r[q*4+2], a1);
                a0 = fmaf(uv.w, w0[q*4+3], a0);  a1 = fmaf(uv.w, w1r[q*4+3], a1);
            }
            partT[wv * 512 + r * DD + lane]      = a0;
            partT[wv * 512 + r * DD + lane + 64] = a1;
        }
    }
    __syncthreads();
    {
        int d = tid & 127;
        float s = x[((size_t)b * NN + i0) * DD + tid] + b4[d];
        #pragma unroll
        for (int w = 0; w < 8; ++w) s += partT[w * 512 + tid];
        resS[tid] = s;
    }
    __syncthreads();

    // ---- LayerNorm: waves 0-3, one row each, 2 d's per lane
    if (wv < 4) {
        const int r = wv, l = lane;
        const float2 v = *(const float2*)&resS[r * DD + l * 2];
        float s1 = v.x + v.y;
        float s2 = v.x * v.x + v.y * v.y;
        #pragma unroll
        for (int m = 32; m; m >>= 1) {
            s1 += __shfl_xor(s1, m);
            s2 += __shfl_xor(s2, m);
        }
        const float mu = s1 * (1.f / DD);
        const float rs = rsqrtf(s2 * (1.f / DD) - mu * mu + LN_EPS);
        const int d = l * 2;
        const float2 gv = *(const float2*)&g[d];
        const float2 bv = *(const float2*)&bet[d];
        float2 o;
        o.x = (v.x - mu) * rs * gv.x + bv.x;
        o.y = (v.y - mu) * rs * gv.y + bv.y;
        *(float2*)&out[((size_t)b * NN + i0 + r) * DD + d] = o;
    }
}

extern "C" void kernel_launch(void* const* d_in, const int* in_sizes, int n_in,
                              void* d_out, int out_size, void* d_ws, size_t ws_size,
                              hipStream_t stream) {
    (void)in_sizes; (void)n_in; (void)out_size; (void)ws_size;
    const float* x      = (const float*)d_in[0];
    const float* adj    = (const float*)d_in[1];
    const float* msg_w1 = (const float*)d_in[2];
    const float* msg_b1 = (const float*)d_in[3];
    const float* msg_w2 = (const float*)d_in[4];
    const float* msg_b2 = (const float*)d_in[5];
    const float* upd_w1 = (const float*)d_in[6];
    const float* upd_b1 = (const float*)d_in[7];
    const float* upd_w2 = (const float*)d_in[8];
    const float* upd_b2 = (const float*)d_in[9];
    const float* ln_g   = (const float*)d_in[10];
    const float* ln_b   = (const float*)d_in[11];
    float* out = (float*)d_out;

    const size_t BND = (size_t)BB * NN * DD;
    float* ws  = (float*)d_ws;
    float* hi  = ws;            // B*N*D
    float* hjb = ws + BND;      // B*N*D
    float* xw3 = ws + 2 * BND;  // B*N*D

    k_proj<<<dim3(256), dim3(512), 0, stream>>>(x, msg_w1, msg_b1, upd_w1, upd_b1,
                                                hi, hjb, xw3);
    k_fused<<<dim3(512), dim3(512), 0, stream>>>(adj, x, hi, hjb, xw3,
                                                 msg_w2, msg_b2,
                                                 upd_w1, upd_w2, upd_b2,
                                                 ln_g, ln_b, out);
}

// Round 11
// 27.170 us; speedup vs baseline: 2.9649x; 2.9649x over previous
//
#include <hip/hip_runtime.h>

#define BB 8
#define NN 256
#define DD 128
#define LN_EPS 1e-5f

// ---------------------------------------------------------------------------
// k_proj: hi = x @ w1[:D],  hjb = x @ w1[D:] + b1
// grid 256 blocks (8 rows) x 512 threads. XCD-affinity: batch = bid & 7 so
// all blocks of one batch share one XCD's L2 (and match k_fused's mapping).
// ---------------------------------------------------------------------------
__global__ __launch_bounds__(512) void k_proj(const float* __restrict__ x,
                                              const float* __restrict__ w1,
                                              const float* __restrict__ b1,
                                              float* __restrict__ hi,
                                              float* __restrict__ hjb) {
    __shared__ float xs[8][DD];        // 4KB
    __shared__ float part_a[4][8][DD]; // 16KB
    __shared__ float part_b[4][8][DD]; // 16KB
    const int bid  = blockIdx.x;
    const int row0 = (bid & 7) * NN + (bid >> 3) * 8;   // XCD-affine
    const int tid  = threadIdx.x;
    #pragma unroll
    for (int t = tid; t < 8 * DD; t += 512)
        xs[t >> 7][t & 127] = x[row0 * DD + t];
    __syncthreads();

    const int dp = tid & 127;
    const int kg = tid >> 7;     // 0..3
    const int kb = kg * 32;

    float acc_a[8] = {}, acc_b[8] = {};
    #pragma unroll
    for (int k4 = 0; k4 < 8; ++k4) {
        const int k0 = kb + k4 * 4;
        float wa[4], wb[4];
        #pragma unroll
        for (int q = 0; q < 4; ++q) {
            wa[q] = w1[(k0 + q) * DD + dp];
            wb[q] = w1[(DD + k0 + q) * DD + dp];
        }
        #pragma unroll
        for (int r = 0; r < 8; ++r) {
            const float4 xv = *(const float4*)&xs[r][k0];   // LDS broadcast
            acc_a[r] = fmaf(xv.x, wa[0], acc_a[r]);
            acc_a[r] = fmaf(xv.y, wa[1], acc_a[r]);
            acc_a[r] = fmaf(xv.z, wa[2], acc_a[r]);
            acc_a[r] = fmaf(xv.w, wa[3], acc_a[r]);
            acc_b[r] = fmaf(xv.x, wb[0], acc_b[r]);
            acc_b[r] = fmaf(xv.y, wb[1], acc_b[r]);
            acc_b[r] = fmaf(xv.z, wb[2], acc_b[r]);
            acc_b[r] = fmaf(xv.w, wb[3], acc_b[r]);
        }
    }
    #pragma unroll
    for (int r = 0; r < 8; ++r) {
        part_a[kg][r][dp] = acc_a[r];
        part_b[kg][r][dp] = acc_b[r];
    }
    __syncthreads();
    #pragma unroll
    for (int m = 0; m < 2; ++m) {
        int idx = tid + m * 512;            // 0..1023
        int r = idx >> 7, d = idx & 127;
        float sa = part_a[0][r][d] + part_a[1][r][d] + part_a[2][r][d] + part_a[3][r][d];
        float sb = part_b[0][r][d] + part_b[1][r][d] + part_b[2][r][d] + part_b[3][r][d];
        hi [(row0 + r) * DD + d] = sa;
        hjb[(row0 + r) * DD + d] = sb + b1[d];
    }
}

// ---------------------------------------------------------------------------
// k_fused: per block (8 rows): pair accumulation (s, asum stay in LDS) then
// the whole tail. 256 blocks x 512 threads. XCD-affinity: b = bid & 7.
//
// LDS plan (floats):
//   [    0,  8192) hjs[64][128]   -> later part[8][8][128]
//   [ 8192, 10240) a_t[8][256]    -> later u1s[8][128] | resS[8][128]
//   [10240, 11264) xs[8][128]
//   [11264, 13312) sspart[16][128]; lower half -> ss, upper half -> aggs
//   [13312, 13320) asum_s[8]
// ---------------------------------------------------------------------------
__global__ __launch_bounds__(512) void k_fused(const float* __restrict__ adj,
                                               const float* __restrict__ x,
                                               const float* __restrict__ hi,
                                               const float* __restrict__ hjb,
                                               const float* __restrict__ w2,
                                               const float* __restrict__ b2,
                                               const float* __restrict__ w3,
                                               const float* __restrict__ b3,
                                               const float* __restrict__ w4,
                                               const float* __restrict__ b4,
                                               const float* __restrict__ g,
                                               const float* __restrict__ bet,
                                               float* __restrict__ out) {
    __shared__ float smem[13320];
    float* const a_t    = smem + 8192;    // [8][256]
    float* const xs     = smem + 10240;   // [8][128]
    float* const ssp    = smem + 11264;   // [16][128]
    float* const aggs   = smem + 12288;   // [8][128] (upper half of ssp)
    float* const u1s    = smem + 8192;    // [8][128] (aliases dead a_t)
    float* const resS   = smem + 9216;    // [8][128] (aliases dead a_t)
    float* const part   = smem;           // [8][8][128] (aliases dead hjs)
    float* const asum_s = smem + 13312;   // [8]

    const int bid = blockIdx.x;
    const int b   = bid & 7;              // XCD-affine batch
    const int i0  = (bid >> 3) * 8;
    const int tid = threadIdx.x;

    // ---- stage masked adjacency rows + x rows
    #pragma unroll
    for (int t = 0; t < 4; ++t) {
        int idx = tid + t * 512;            // 0..2047
        int il = idx >> 8, j = idx & 255;
        int i_g = i0 + il;
        float av = adj[((size_t)b * NN + i_g) * NN + j];
        a_t[il * 256 + j] = (j == i_g) ? 0.f : av;
    }
    #pragma unroll
    for (int t = 0; t < 2; ++t) {
        int idx = tid + t * 512;            // 0..1023
        xs[idx] = x[((size_t)b * NN + i0) * DD + idx];
    }
    __syncthreads();

    // ---- asum: one wave per row
    {
        int w = tid >> 6, l = tid & 63;
        float s = a_t[w * 256 + l] + a_t[w * 256 + l + 64]
                + a_t[w * 256 + l + 128] + a_t[w * 256 + l + 192];
        #pragma unroll
        for (int m = 32; m; m >>= 1) s += __shfl_xor(s, m);
        if (l == 0) asum_s[w] = s;
    }

    // ---- pair phase: s[row][d] = sum_j relu(hi+hjb)*a
    const int dq  = tid & 31;       // d-quad
    const int rg  = tid >> 5;       // 0..15
    const int row = rg & 7;
    const int jh  = rg >> 3;
    const float4 hi4 = *(const float4*)&hi[((size_t)b * NN + i0 + row) * DD + dq * 4];
    float4 acc = {0.f, 0.f, 0.f, 0.f};

    for (int jt = 0; jt < 4; ++jt) {
        __syncthreads();   // prev tile reads done
        const float4* src = (const float4*)(hjb + ((size_t)b * NN + jt * 64) * DD);
        float4* dst = (float4*)smem;
        #pragma unroll
        for (int t = 0; t < 4; ++t) dst[tid + t * 512] = src[tid + t * 512];
        __syncthreads();
        const int jb = jh * 32;
        #pragma unroll 8
        for (int jj = 0; jj < 32; ++jj) {
            const int jl = jb + jj;
            const float4 hv = *(const float4*)&smem[jl * 128 + dq * 4];
            const float a = a_t[row * 256 + jt * 64 + jl];
            acc.x = fmaf(fmaxf(hi4.x + hv.x, 0.f), a, acc.x);
            acc.y = fmaf(fmaxf(hi4.y + hv.y, 0.f), a, acc.y);
            acc.z = fmaf(fmaxf(hi4.z + hv.z, 0.f), a, acc.z);
            acc.w = fmaf(fmaxf(hi4.w + hv.w, 0.f), a, acc.w);
        }
    }
    __syncthreads();       // last hjs reads done
    *(float4*)&ssp[rg * 128 + dq * 4] = acc;
    __syncthreads();
    // combine j-halves into lower half
    #pragma unroll
    for (int t = 0; t < 2; ++t) {
        int idx = tid + t * 512;
        int r = idx >> 7, d = idx & 127;
        ssp[r * 128 + d] += ssp[(r + 8) * 128 + d];
    }
    __syncthreads();

    // ---- tail mapping: 2 output cols/thread, 8-way k-split
    const int dp = tid & 63;            // cols dp, dp+64
    const int kg = tid >> 6;            // 0..7 (wave-uniform)
    const int kb = kg * 16;

    // ---- stage A: agg = ss @ w2 (+ b2*asum at combine)
    {
        float wv0[16], wv1[16];
        #pragma unroll
        for (int k = 0; k < 16; ++k) {
            wv0[k] = w2[(kb + k) * DD + dp];
            wv1[k] = w2[(kb + k) * DD + dp + 64];
        }
        #pragma unroll
        for (int r = 0; r < 8; ++r) {
            float a0 = 0.f, a1 = 0.f;
            #pragma unroll
            for (int q = 0; q < 4; ++q) {
                const float4 sv = *(const float4*)&ssp[r * 128 + kb + q * 4];
                a0 = fmaf(sv.x, wv0[q*4+0], a0); a1 = fmaf(sv.x, wv1[q*4+0], a1);
                a0 = fmaf(sv.y, wv0[q*4+1], a0); a1 = fmaf(sv.y, wv1[q*4+1], a1);
                a0 = fmaf(sv.z, wv0[q*4+2], a0); a1 = fmaf(sv.z, wv1[q*4+2], a1);
                a0 = fmaf(sv.w, wv0[q*4+3], a0); a1 = fmaf(sv.w, wv1[q*4+3], a1);
            }
            part[kg * 1024 + r * 128 + dp]      = a0;
            part[kg * 1024 + r * 128 + dp + 64] = a1;
        }
    }
    __syncthreads();
    #pragma unroll
    for (int m = 0; m < 2; ++m) {
        int idx = tid + m * 512;
        int r = idx >> 7, d = idx & 127;
        float s = part[r * 128 + d];
        #pragma unroll
        for (int w = 1; w < 8; ++w) s += part[w * 1024 + r * 128 + d];
        aggs[r * 128 + d] = s + b2[d] * asum_s[r];
    }
    __syncthreads();

    // ---- stage B: u1 = relu(x@w3a + agg@w3b + b3)
    {
        float wa0[16], wa1[16], wb0[16], wb1[16];
        #pragma unroll
        for (int k = 0; k < 16; ++k) {
            wa0[k] = w3[(kb + k) * DD + dp];
            wa1[k] = w3[(kb + k) * DD + dp + 64];
            wb0[k] = w3[(DD + kb + k) * DD + dp];
            wb1[k] = w3[(DD + kb + k) * DD + dp + 64];
        }
        #pragma unroll
        for (int r = 0; r < 8; ++r) {
            float a0 = 0.f, a1 = 0.f;
            #pragma unroll
            for (int q = 0; q < 4; ++q) {
                const float4 xv = *(const float4*)&xs[r * 128 + kb + q * 4];
                const float4 av = *(const float4*)&aggs[r * 128 + kb + q * 4];
                a0 = fmaf(xv.x, wa0[q*4+0], a0); a1 = fmaf(xv.x, wa1[q*4+0], a1);
                a0 = fmaf(xv.y, wa0[q*4+1], a0); a1 = fmaf(xv.y, wa1[q*4+1], a1);
                a0 = fmaf(xv.z, wa0[q*4+2], a0); a1 = fmaf(xv.z, wa1[q*4+2], a1);
                a0 = fmaf(xv.w, wa0[q*4+3], a0); a1 = fmaf(xv.w, wa1[q*4+3], a1);
                a0 = fmaf(av.x, wb0[q*4+0], a0); a1 = fmaf(av.x, wb1[q*4+0], a1);
                a0 = fmaf(av.y, wb0[q*4+1], a0); a1 = fmaf(av.y, wb1[q*4+1], a1);
                a0 = fmaf(av.z, wb0[q*4+2], a0); a1 = fmaf(av.z, wb1[q*4+2], a1);
                a0 = fmaf(av.w, wb0[q*4+3], a0); a1 = fmaf(av.w, wb1[q*4+3], a1);
            }
            part[kg * 1024 + r * 128 + dp]      = a0;
            part[kg * 1024 + r * 128 + dp + 64] = a1;
        }
    }
    __syncthreads();
    #pragma unroll
    for (int m = 0; m < 2; ++m) {
        int idx = tid + m * 512;
        int r = idx >> 7, d = idx & 127;
        float s = part[r * 128 + d];
        #pragma unroll
        for (int w = 1; w < 8; ++w) s += part[w * 1024 + r * 128 + d];
        u1s[r * 128 + d] = fmaxf(s + b3[d], 0.f);
    }
    __syncthreads();

    // ---- stage C: upd = u1 @ w4
    {
        float wv0[16], wv1[16];
        #pragma unroll
        for (int k = 0; k < 16; ++k) {
            wv0[k] = w4[(kb + k) * DD + dp];
            wv1[k] = w4[(kb + k) * DD + dp + 64];
        }
        #pragma unroll
        for (int r = 0; r < 8; ++r) {
            float a0 = 0.f, a1 = 0.f;
            #pragma unroll
            for (int q = 0; q < 4; ++q) {
                const float4 uv = *(const float4*)&u1s[r * 128 + kb + q * 4];
                a0 = fmaf(uv.x, wv0[q*4+0], a0); a1 = fmaf(uv.x, wv1[q*4+0], a1);
                a0 = fmaf(uv.y, wv0[q*4+1], a0); a1 = fmaf(uv.y, wv1[q*4+1], a1);
                a0 = fmaf(uv.z, wv0[q*4+2], a0); a1 = fmaf(uv.z, wv1[q*4+2], a1);
                a0 = fmaf(uv.w, wv0[q*4+3], a0); a1 = fmaf(uv.w, wv1[q*4+3], a1);
            }
            part[kg * 1024 + r * 128 + dp]      = a0;
            part[kg * 1024 + r * 128 + dp + 64] = a1;
        }
    }
    __syncthreads();
    #pragma unroll
    for (int m = 0; m < 2; ++m) {
        int idx = tid + m * 512;
        int r = idx >> 7, d = idx & 127;
        float s = part[r * 128 + d];
        #pragma unroll
        for (int w = 1; w < 8; ++w) s += part[w * 1024 + r * 128 + d];
        resS[r * 128 + d] = xs[r * 128 + d] + s + b4[d];
    }
    __syncthreads();

    // ---- LayerNorm: one wave per row, 2 d's per lane
    {
        const int r = tid >> 6, l = tid & 63;
        const float2 v = *(const float2*)&resS[r * 128 + l * 2];
        float s1 = v.x + v.y;
        float s2 = v.x * v.x + v.y * v.y;
        #pragma unroll
        for (int m = 32; m; m >>= 1) {
            s1 += __shfl_xor(s1, m);
            s2 += __shfl_xor(s2, m);
        }
        const float mu = s1 * (1.f / DD);
        const float rs = rsqrtf(s2 * (1.f / DD) - mu * mu + LN_EPS);
        const int d = l * 2;
        const float2 gv = *(const float2*)&g[d];
        const float2 bv = *(const float2*)&bet[d];
        float2 o;
        o.x = (v.x - mu) * rs * gv.x + bv.x;
        o.y = (v.y - mu) * rs * gv.y + bv.y;
        *(float2*)&out[((size_t)b * NN + i0 + r) * DD + d] = o;
    }
}

extern "C" void kernel_launch(void* const* d_in, const int* in_sizes, int n_in,
                              void* d_out, int out_size, void* d_ws, size_t ws_size,
                              hipStream_t stream) {
    (void)in_sizes; (void)n_in; (void)out_size; (void)ws_size;
    const float* x      = (const float*)d_in[0];
    const float* adj    = (const float*)d_in[1];
    const float* msg_w1 = (const float*)d_in[2];
    const float* msg_b1 = (const float*)d_in[3];
    const float* msg_w2 = (const float*)d_in[4];
    const float* msg_b2 = (const float*)d_in[5];
    const float* upd_w1 = (const float*)d_in[6];
    const float* upd_b1 = (const float*)d_in[7];
    const float* upd_w2 = (const float*)d_in[8];
    const float* upd_b2 = (const float*)d_in[9];
    const float* ln_g   = (const float*)d_in[10];
    const float* ln_b   = (const float*)d_in[11];
    float* out = (float*)d_out;

    const size_t BND = (size_t)BB * NN * DD;
    float* ws  = (float*)d_ws;
    float* hi  = ws;            // B*N*D
    float* hjb = ws + BND;      // B*N*D

    k_proj<<<dim3(256), dim3(512), 0, stream>>>(x, msg_w1, msg_b1, hi, hjb);
    k_fused<<<dim3(256), dim3(512), 0, stream>>>(adj, x, hi, hjb,
                                                 msg_w2, msg_b2,
                                                 upd_w1, upd_b1, upd_w2, upd_b2,
                                                 ln_g, ln_b, out);
}